// Round 5
// baseline (838.035 us; speedup 1.0000x reference)
//
#include <hip/hip_runtime.h>
#include <math.h>

#define NB 4
#define NS 2048
#define NE 1024
#define NH 16
#define ND 64
#define NM (NB*NS)   // 8192 rows

typedef __attribute__((ext_vector_type(8))) short bf16x8v;
typedef __attribute__((ext_vector_type(4))) float f32x4v;

__device__ __forceinline__ ushort f2bf(float f) {
    union { float f; unsigned u; } v; v.f = f;
    unsigned r = v.u + 0x7FFFu + ((v.u >> 16) & 1u);   // RNE
    return (ushort)(r >> 16);
}
__device__ __forceinline__ float bf2f(ushort h) {
    union { unsigned u; float f; } v; v.u = ((unsigned)h) << 16;
    return v.f;
}

// ---------------------------------------------------------------------------
// fp32 -> bf16 split (hi + lo residual), vectorized float4
// ---------------------------------------------------------------------------
__global__ __launch_bounds__(256)
void cvt_split_kernel(const float* __restrict__ src,
                      ushort* __restrict__ hi, ushort* __restrict__ lo, int n4)
{
    int i = blockIdx.x * blockDim.x + threadIdx.x;
    const int stride = gridDim.x * blockDim.x;
    for (; i < n4; i += stride) {
        float4 v = ((const float4*)src)[i];
        ushort4 h, l;
        h.x = f2bf(v.x); l.x = f2bf(v.x - bf2f(h.x));
        h.y = f2bf(v.y); l.y = f2bf(v.y - bf2f(h.y));
        h.z = f2bf(v.z); l.z = f2bf(v.z - bf2f(h.z));
        h.w = f2bf(v.w); l.w = f2bf(v.w - bf2f(h.w));
        ((ushort4*)hi)[i] = h;
        ((ushort4*)lo)[i] = l;
    }
}

// ---------------------------------------------------------------------------
// Transpose + split convert: src f32 [Z][K][N] -> dst bf16 [Z][N][K] (hi, lo)
// 64x64 tiles; grid = (K/64, N/64, Z), block = 256.
// ---------------------------------------------------------------------------
__global__ __launch_bounds__(256)
void transpose_cvt_split_kernel(const float* __restrict__ src,
                                ushort* __restrict__ hi, ushort* __restrict__ lo,
                                int K, int N)
{
    __shared__ float T[64][68];
    const int k0 = blockIdx.x * 64;
    const int n0 = blockIdx.y * 64;
    const size_t zoff = (size_t)blockIdx.z * K * N;
    const int t = threadIdx.x;

    {   // read: coalesced along N
        const int c4 = t & 15;
        const int kr = t >> 4;
        #pragma unroll
        for (int j = 0; j < 4; ++j) {
            const int k = k0 + kr + 16 * j;
            float4 v = *(const float4*)&src[zoff + (size_t)k * N + n0 + c4 * 4];
            T[c4*4+0][kr + 16*j] = v.x;
            T[c4*4+1][kr + 16*j] = v.y;
            T[c4*4+2][kr + 16*j] = v.z;
            T[c4*4+3][kr + 16*j] = v.w;
        }
    }
    __syncthreads();
    {   // write: coalesced along K
        const int k4 = t & 15;
        const int nr = t >> 4;
        #pragma unroll
        for (int j = 0; j < 4; ++j) {
            const int nl = nr + 16 * j;
            ushort4 h, l;
            float x;
            x = T[nl][k4*4+0]; h.x = f2bf(x); l.x = f2bf(x - bf2f(h.x));
            x = T[nl][k4*4+1]; h.y = f2bf(x); l.y = f2bf(x - bf2f(h.y));
            x = T[nl][k4*4+2]; h.z = f2bf(x); l.z = f2bf(x - bf2f(h.z));
            x = T[nl][k4*4+3]; h.w = f2bf(x); l.w = f2bf(x - bf2f(h.w));
            const size_t o = zoff + (size_t)(n0 + nl) * K + k0 + k4 * 4;
            *(ushort4*)&hi[o] = h;
            *(ushort4*)&lo[o] = l;
        }
    }
}

// ---------------------------------------------------------------------------
// bf16x3 MFMA GEMM core. A[M][1024] k-contig, Bt[Ncols][1024] n-major, both
// as (hi, lo) bf16 pairs. Tile 128x128, BK=64, 4 waves (2x2), 64x64/wave.
// C = AhiBhi + AhiBlo + AloBhi  (fp32-grade accuracy).
// LDS [128][64] bf16 tiles, T2 XOR swizzle: chunk ^= (row&7).
// k-map consistency: A and B fragments use the identical (lane,slot)->k map
// (k = s*32 + (lane>>4)*8 + j), so the result is invariant to the HW's
// internal A/B k-ordering. D-layout is the m89-verified col=lane&15,
// row=(lane>>4)*4+reg.
// ---------------------------------------------------------------------------
__device__ __forceinline__ void gemm_core_bf16x3(
    const ushort* __restrict__ Ahi, const ushort* __restrict__ Alo,
    const ushort* __restrict__ Bhi, const ushort* __restrict__ Blo,
    ushort* AsH, ushort* AsL, ushort* BsH, ushort* BsL,
    int m0, int n0, int t, f32x4v acc[4][4])
{
    const int l  = t & 63;
    const int w  = t >> 6;
    const int wr = w >> 1, wc = w & 1;
    const int lr = l & 15, lg = l >> 4;
    const int sc = t & 7;      // staging: 16B chunk within a 64-elem row
    const int sr = t >> 3;     // staging: row 0..31 (+32j)

    for (int k0 = 0; k0 < NE; k0 += 64) {
        __syncthreads();
        #pragma unroll
        for (int j = 0; j < 4; ++j) {
            const int row  = sr + 32 * j;
            const int wofs = row * 64 + ((sc ^ (row & 7)) * 8);
            const size_t aofs = (size_t)(m0 + row) * NE + k0 + sc * 8;
            const size_t bofs = (size_t)(n0 + row) * NE + k0 + sc * 8;
            *(float4*)&AsH[wofs] = *(const float4*)(Ahi + aofs);
            *(float4*)&AsL[wofs] = *(const float4*)(Alo + aofs);
            *(float4*)&BsH[wofs] = *(const float4*)(Bhi + bofs);
            *(float4*)&BsL[wofs] = *(const float4*)(Blo + bofs);
        }
        __syncthreads();
        #pragma unroll
        for (int s = 0; s < 2; ++s) {
            bf16x8v afH[4], afL[4], bfH[4], bfL[4];
            #pragma unroll
            for (int i = 0; i < 4; ++i) {
                const int ra = wr * 64 + i * 16 + lr;
                const int ca = ((s * 4 + lg) ^ (ra & 7)) * 8;
                afH[i] = *(const bf16x8v*)&AsH[ra * 64 + ca];
                afL[i] = *(const bf16x8v*)&AsL[ra * 64 + ca];
                const int rb = wc * 64 + i * 16 + lr;
                const int cb = ((s * 4 + lg) ^ (rb & 7)) * 8;
                bfH[i] = *(const bf16x8v*)&BsH[rb * 64 + cb];
                bfL[i] = *(const bf16x8v*)&BsL[rb * 64 + cb];
            }
            #pragma unroll
            for (int i = 0; i < 4; ++i)
                #pragma unroll
                for (int j = 0; j < 4; ++j) {
                    acc[i][j] = __builtin_amdgcn_mfma_f32_16x16x32_bf16(afH[i], bfH[j], acc[i][j], 0, 0, 0);
                    acc[i][j] = __builtin_amdgcn_mfma_f32_16x16x32_bf16(afH[i], bfL[j], acc[i][j], 0, 0, 0);
                    acc[i][j] = __builtin_amdgcn_mfma_f32_16x16x32_bf16(afL[i], bfH[j], acc[i][j], 0, 0, 0);
                }
        }
    }
}

// ---------------------------------------------------------------------------
// QKV projection: X[8192][1024] @ Wt{q,k,v}[1024 (h*64+d)][1024 (e)]
// z==0 -> Q bf16 hi/lo, pre-scaled by D^-0.5 ; z==1 -> K bf16 hi/lo ;
// z==2 -> V fp32.  All in [b,h,s,d].
// ---------------------------------------------------------------------------
__global__ __launch_bounds__(256, 2)
void gemm_qkv_kernel(const ushort* __restrict__ Xhi, const ushort* __restrict__ Xlo,
                     const ushort* __restrict__ WqH, const ushort* __restrict__ WqL,
                     const ushort* __restrict__ WkH, const ushort* __restrict__ WkL,
                     const ushort* __restrict__ WvH, const ushort* __restrict__ WvL,
                     ushort* __restrict__ Qhi, ushort* __restrict__ Qlo,
                     ushort* __restrict__ Khi, ushort* __restrict__ Klo,
                     float* __restrict__ Vb)
{
    __shared__ ushort AsH[128 * 64], AsL[128 * 64], BsH[128 * 64], BsL[128 * 64];
    const int z = blockIdx.z;
    const ushort* __restrict__ BtH = (z == 0) ? WqH : (z == 1) ? WkH : WvH;
    const ushort* __restrict__ BtL = (z == 0) ? WqL : (z == 1) ? WkL : WvL;
    const int m0 = blockIdx.x * 128;
    const int n0 = blockIdx.y * 128;
    const int t  = threadIdx.x;
    const int l  = t & 63;
    const int w  = t >> 6;
    const int wr = w >> 1, wc = w & 1;
    const int lr = l & 15, lg = l >> 4;

    f32x4v acc[4][4];
    #pragma unroll
    for (int i = 0; i < 4; ++i)
        #pragma unroll
        for (int j = 0; j < 4; ++j)
            #pragma unroll
            for (int q = 0; q < 4; ++q) acc[i][j][q] = 0.f;

    gemm_core_bf16x3(Xhi, Xlo, BtH, BtL, AsH, AsL, BsH, BsL, m0, n0, t, acc);

    ushort* __restrict__ Hi = (z == 0) ? Qhi : Khi;
    ushort* __restrict__ Lo = (z == 0) ? Qlo : Klo;
    const float qscale = (z == 0) ? 0.125f : 1.0f;

    // D frag (m89): col = lane&15, row = (lane>>4)*4 + q
    #pragma unroll
    for (int i = 0; i < 4; ++i)
        #pragma unroll
        for (int j = 0; j < 4; ++j) {
            const int n  = n0 + wc * 64 + j * 16 + lr;
            const int hh = n >> 6, d = n & 63;
            #pragma unroll
            for (int q = 0; q < 4; ++q) {
                const int m  = m0 + wr * 64 + i * 16 + lg * 4 + q;
                const int bb = m >> 11, ss = m & 2047;
                const size_t idx = (((size_t)(bb * NH + hh)) * NS + ss) * ND + d;
                if (z == 2) {
                    Vb[idx] = acc[i][j][q];
                } else {
                    const float x = acc[i][j][q] * qscale;
                    const ushort h = f2bf(x);
                    Hi[idx] = h;
                    Lo[idx] = f2bf(x - bf2f(h));
                }
            }
        }
}

// ---------------------------------------------------------------------------
// Output projection: A[8192][1024] @ Wot[1024][1024] + bias (bf16x3 MFMA)
// ---------------------------------------------------------------------------
__global__ __launch_bounds__(256, 2)
void gemm_out_kernel(const ushort* __restrict__ AbH, const ushort* __restrict__ AbL,
                     const ushort* __restrict__ WoH, const ushort* __restrict__ WoL,
                     const float* __restrict__ bo,
                     float* __restrict__ Out)
{
    __shared__ ushort AsH[128 * 64], AsL[128 * 64], BsH[128 * 64], BsL[128 * 64];
    const int m0 = blockIdx.x * 128;
    const int n0 = blockIdx.y * 128;
    const int t  = threadIdx.x;
    const int l  = t & 63;
    const int w  = t >> 6;
    const int wr = w >> 1, wc = w & 1;
    const int lr = l & 15, lg = l >> 4;

    f32x4v acc[4][4];
    #pragma unroll
    for (int i = 0; i < 4; ++i)
        #pragma unroll
        for (int j = 0; j < 4; ++j)
            #pragma unroll
            for (int q = 0; q < 4; ++q) acc[i][j][q] = 0.f;

    gemm_core_bf16x3(AbH, AbL, WoH, WoL, AsH, AsL, BsH, BsL, m0, n0, t, acc);

    #pragma unroll
    for (int i = 0; i < 4; ++i)
        #pragma unroll
        for (int j = 0; j < 4; ++j) {
            const int n = n0 + wc * 64 + j * 16 + lr;
            const float bias = bo[n];
            #pragma unroll
            for (int q = 0; q < 4; ++q) {
                const int m = m0 + wr * 64 + i * 16 + lg * 4 + q;
                Out[(size_t)m * NE + n] = acc[i][j][q] + bias;
            }
        }
}

// ---------------------------------------------------------------------------
// Causal flash attention. QK^T via bf16x3 MFMA (Q pre-scaled), softmax fp32
// (exact), PV via fp32 VALU (exact). Block = 256 thr (4 waves), Q-tile 64
// rows (16/wave), K-tile 64. Epilogue writes O directly as bf16 hi/lo in
// [b,s,h*d] (feeds gemm_out; saves a separate cvt pass + 67 MB traffic).
// MFMA-side lane roles: w = wave, g = lane>>4, c = lane&15.
//   S fragment f: S[q0+16w+4g+q][j0+16f+c] in sf[f][q]  (m89 D-layout).
// PV-side thread roles (independent): ty = t>>4 (q-row grp), tx = t&15 (d).
// ---------------------------------------------------------------------------
__global__ __launch_bounds__(256, 2)
void attn_kernel(const ushort* __restrict__ Qhi, const ushort* __restrict__ Qlo,
                 const ushort* __restrict__ Khi, const ushort* __restrict__ Klo,
                 const float* __restrict__ V,
                 ushort* __restrict__ ObbH, ushort* __restrict__ ObbL)
{
    __shared__ ushort KsH[64 * 64], KsL[64 * 64];   // K tile, XOR-swizzled
    __shared__ float  Vs[64][68];                   // V tile [key][d]
    __shared__ float  Ps[64][68];                   // P^T [key][q_local]
    __shared__ float  fac_s[64];                    // per-row rescale / 1/l

    const int qt = blockIdx.x;
    const int q0 = qt * 64;
    const int bh = blockIdx.y;
    const int bb = bh >> 4, hh = bh & 15;
    const size_t base = (size_t)bh * NS * ND;

    const int t  = threadIdx.x;
    const int l  = t & 63;
    const int w  = t >> 6;
    const int g  = l >> 4;
    const int c  = l & 15;
    const int tx = t & 15, ty = t >> 4;
    const int sc = t & 7,  sr = t >> 3;

    // preload Q A-fragments from global: row q0+16w+c, k = s*32 + g*8 + j
    bf16x8v qh[2], ql[2];
    {
        const size_t qrow = base + (size_t)(q0 + 16 * w + c) * ND;
        #pragma unroll
        for (int s = 0; s < 2; ++s) {
            qh[s] = *(const bf16x8v*)&Qhi[qrow + s * 32 + g * 8];
            ql[s] = *(const bf16x8v*)&Qlo[qrow + s * 32 + g * 8];
        }
    }

    float m_run[4], l_run[4], o_acc[4][4];
    #pragma unroll
    for (int q = 0; q < 4; ++q) { m_run[q] = -INFINITY; l_run[q] = 0.f; }
    #pragma unroll
    for (int i = 0; i < 4; ++i)
        #pragma unroll
        for (int j = 0; j < 4; ++j) o_acc[i][j] = 0.f;

    for (int j0 = 0; j0 <= q0; j0 += 64) {
        __syncthreads();   // A: previous tile's PV done; buffers free
        // stage K hi/lo (swizzled, GEMM pattern) and V (f32)
        #pragma unroll
        for (int rr = 0; rr < 2; ++rr) {
            const int row  = sr + 32 * rr;
            const int wofs = row * 64 + ((sc ^ (row & 7)) * 8);
            const size_t kofs = base + (size_t)(j0 + row) * ND + sc * 8;
            *(float4*)&KsH[wofs] = *(const float4*)&Khi[kofs];
            *(float4*)&KsL[wofs] = *(const float4*)&Klo[kofs];
        }
        #pragma unroll
        for (int it = 0; it < 4; ++it) {
            const int row = ty + 16 * it;
            *(float4*)&Vs[row][tx * 4] =
                *(const float4*)&V[base + (size_t)(j0 + row) * ND + tx * 4];
        }
        __syncthreads();   // B: tiles visible

        // QK^T: bf16x3, fragments over 4 key groups x 2 k-steps
        f32x4v sf[4];
        #pragma unroll
        for (int f = 0; f < 4; ++f)
            #pragma unroll
            for (int q = 0; q < 4; ++q) sf[f][q] = 0.f;
        #pragma unroll
        for (int s = 0; s < 2; ++s) {
            #pragma unroll
            for (int f = 0; f < 4; ++f) {
                const int rb = 16 * f + c;
                const int cb = ((s * 4 + g) ^ (c & 7)) * 8;
                bf16x8v kh = *(const bf16x8v*)&KsH[rb * 64 + cb];
                bf16x8v kl = *(const bf16x8v*)&KsL[rb * 64 + cb];
                sf[f] = __builtin_amdgcn_mfma_f32_16x16x32_bf16(qh[s], kh, sf[f], 0, 0, 0);
                sf[f] = __builtin_amdgcn_mfma_f32_16x16x32_bf16(qh[s], kl, sf[f], 0, 0, 0);
                sf[f] = __builtin_amdgcn_mfma_f32_16x16x32_bf16(ql[s], kh, sf[f], 0, 0, 0);
            }
        }

        // causal mask (only when some key can exceed some row of this wave)
        if (j0 + 63 > q0 + 16 * w) {
            #pragma unroll
            for (int f = 0; f < 4; ++f) {
                const int key = j0 + 16 * f + c;
                #pragma unroll
                for (int q = 0; q < 4; ++q) {
                    const int row = q0 + 16 * w + 4 * g + q;
                    if (key > row) sf[f][q] = -INFINITY;
                }
            }
        }

        // online softmax (row stats across the 16 c-lanes of group g)
        float fac[4];
        #pragma unroll
        for (int q = 0; q < 4; ++q) {
            float rm = fmaxf(fmaxf(sf[0][q], sf[1][q]), fmaxf(sf[2][q], sf[3][q]));
            rm = fmaxf(rm, __shfl_xor(rm, 1));
            rm = fmaxf(rm, __shfl_xor(rm, 2));
            rm = fmaxf(rm, __shfl_xor(rm, 4));
            rm = fmaxf(rm, __shfl_xor(rm, 8));
            const float mn = fmaxf(m_run[q], rm);
            float rs = 0.f;
            #pragma unroll
            for (int f = 0; f < 4; ++f) {
                const float p = __expf(sf[f][q] - mn);   // exp(-inf)=0 masks
                sf[f][q] = p;
                rs += p;
            }
            rs += __shfl_xor(rs, 1);
            rs += __shfl_xor(rs, 2);
            rs += __shfl_xor(rs, 4);
            rs += __shfl_xor(rs, 8);
            fac[q] = __expf(m_run[q] - mn);
            m_run[q] = mn;
            l_run[q] = l_run[q] * fac[q] + rs;
        }

        // write P^T (f32x4 per fragment: keys 16f+c, q-rows 16w+4g..+3)
        #pragma unroll
        for (int f = 0; f < 4; ++f)
            *(f32x4v*)&Ps[16 * f + c][16 * w + 4 * g] = sf[f];
        if (c == 0) {
            f32x4v fv;
            fv[0] = fac[0]; fv[1] = fac[1]; fv[2] = fac[2]; fv[3] = fac[3];
            *(f32x4v*)&fac_s[16 * w + 4 * g] = fv;
        }
        __syncthreads();   // C: P, fac visible

        // PV (fp32 VALU, exact): rescale then accumulate
        #pragma unroll
        for (int i = 0; i < 4; ++i) {
            const float fi = fac_s[ty * 4 + i];
            #pragma unroll
            for (int j = 0; j < 4; ++j) o_acc[i][j] *= fi;
        }
        #pragma unroll 4
        for (int k = 0; k < 64; ++k) {
            float4 a = *(const float4*)&Ps[k][ty * 4];
            float4 b = *(const float4*)&Vs[k][tx * 4];
            float av[4] = {a.x, a.y, a.z, a.w};
            float bv[4] = {b.x, b.y, b.z, b.w};
            #pragma unroll
            for (int i = 0; i < 4; ++i)
                #pragma unroll
                for (int j = 0; j < 4; ++j)
                    o_acc[i][j] = fmaf(av[i], bv[j], o_acc[i][j]);
        }
    }

    // final 1/l via fac_s (owner lanes), then normalize + split-store
    __syncthreads();
    if ((l & 15) == 0) {
        f32x4v iv;
        iv[0] = 1.f / l_run[0]; iv[1] = 1.f / l_run[1];
        iv[2] = 1.f / l_run[2]; iv[3] = 1.f / l_run[3];
        *(f32x4v*)&fac_s[16 * w + 4 * g] = iv;
    }
    __syncthreads();
    #pragma unroll
    for (int i = 0; i < 4; ++i) {
        const float inv = fac_s[ty * 4 + i];
        const int s = q0 + ty * 4 + i;
        const size_t o = (((size_t)(bb * NS + s) * NH + hh) << 6) + tx * 4;
        ushort4 h4, l4;
        float x;
        x = o_acc[i][0] * inv; h4.x = f2bf(x); l4.x = f2bf(x - bf2f(h4.x));
        x = o_acc[i][1] * inv; h4.y = f2bf(x); l4.y = f2bf(x - bf2f(h4.y));
        x = o_acc[i][2] * inv; h4.z = f2bf(x); l4.z = f2bf(x - bf2f(h4.z));
        x = o_acc[i][3] * inv; h4.w = f2bf(x); l4.w = f2bf(x - bf2f(h4.w));
        *(ushort4*)&ObbH[o] = h4;
        *(ushort4*)&ObbL[o] = l4;
    }
}

// ---------------------------------------------------------------------------
extern "C" void kernel_launch(void* const* d_in, const int* in_sizes, int n_in,
                              void* d_out, int out_size, void* d_ws, size_t ws_size,
                              hipStream_t stream)
{
    (void)in_sizes; (void)n_in; (void)out_size; (void)ws_size;
    const float* X  = (const float*)d_in[0];
    const float* Wq = (const float*)d_in[1];
    const float* Wk = (const float*)d_in[2];
    const float* Wv = (const float*)d_in[3];
    const float* Wo = (const float*)d_in[4];
    const float* bo = (const float*)d_in[5];

    // workspace (~151 MB) with dead-region aliasing
    char* p = (char*)d_ws;
    ushort* Xhi = (ushort*)p; p += (size_t)NM * NE * 2;     // 16.8 MB
    ushort* Xlo = (ushort*)p; p += (size_t)NM * NE * 2;     // 16.8 MB
    ushort* WqH = (ushort*)p; p += (size_t)NE * NE * 2;
    ushort* WqL = (ushort*)p; p += (size_t)NE * NE * 2;
    ushort* WkH = (ushort*)p; p += (size_t)NE * NE * 2;
    ushort* WkL = (ushort*)p; p += (size_t)NE * NE * 2;
    ushort* WvH = (ushort*)p; p += (size_t)NE * NE * 2;
    ushort* WvL = (ushort*)p; p += (size_t)NE * NE * 2;
    ushort* WoH = (ushort*)p; p += (size_t)NE * NE * 2;
    ushort* WoL = (ushort*)p; p += (size_t)NE * NE * 2;
    ushort* Qhi = (ushort*)p; p += (size_t)NM * NE * 2;     // 16.8 MB
    ushort* Qlo = (ushort*)p; p += (size_t)NM * NE * 2;
    ushort* Khi = (ushort*)p; p += (size_t)NM * NE * 2;
    ushort* Klo = (ushort*)p; p += (size_t)NM * NE * 2;
    float*  Vb  = (float*)p;  p += (size_t)NM * NE * 4;     // 33.5 MB
    // aliases over dead regions (X splits are dead after gemm_qkv; they are
    // NOT read by attn, so attn may write its bf16 output there directly):
    ushort* ObbH = Xhi;
    ushort* ObbL = Xlo;

    // 1. split-convert X
    hipLaunchKernelGGL(cvt_split_kernel, dim3(2048), dim3(256), 0, stream,
                       X, Xhi, Xlo, NM * NE / 4);
    // 2. transpose + split-convert weights to n-major bf16
    hipLaunchKernelGGL(transpose_cvt_split_kernel, dim3(16, 1, 16), dim3(256), 0, stream,
                       Wq, WqH, WqL, NE, ND);
    hipLaunchKernelGGL(transpose_cvt_split_kernel, dim3(16, 1, 16), dim3(256), 0, stream,
                       Wk, WkH, WkL, NE, ND);
    hipLaunchKernelGGL(transpose_cvt_split_kernel, dim3(16, 1, 16), dim3(256), 0, stream,
                       Wv, WvH, WvL, NE, ND);
    hipLaunchKernelGGL(transpose_cvt_split_kernel, dim3(16, 16, 1), dim3(256), 0, stream,
                       Wo, WoH, WoL, NE, NE);
    // 3. QKV projection: Q,K -> bf16 hi/lo (Q pre-scaled), V -> fp32
    hipLaunchKernelGGL(gemm_qkv_kernel, dim3(NM/128, NE/128, 3), dim3(256), 0, stream,
                       Xhi, Xlo, WqH, WqL, WkH, WkL, WvH, WvL,
                       Qhi, Qlo, Khi, Klo, Vb);
    // 4. attention (MFMA QK^T + exact fp32 softmax/PV) -> bf16 hi/lo [b,s,h*d]
    hipLaunchKernelGGL(attn_kernel, dim3(NS/64, NB*NH), dim3(256), 0, stream,
                       Qhi, Qlo, Khi, Klo, Vb, ObbH, ObbL);
    // 5. output projection (bf16x3 MFMA) + bias -> d_out
    hipLaunchKernelGGL(gemm_out_kernel, dim3(NM/128, NE/128), dim3(256), 0, stream,
                       ObbH, ObbL, WoH, WoL, bo, (float*)d_out);
}

// Round 6
// 525.969 us; speedup vs baseline: 1.5933x; 1.5933x over previous
//
#include <hip/hip_runtime.h>
#include <math.h>

#define NB 4
#define NS 2048
#define NE 1024
#define NH 16
#define ND 64
#define NM (NB*NS)   // 8192 rows

typedef __attribute__((ext_vector_type(8))) short bf16x8v;
typedef __attribute__((ext_vector_type(4))) float f32x4v;
typedef __attribute__((ext_vector_type(8))) unsigned short u16x8v;

__device__ __forceinline__ ushort f2bf(float f) {
    union { float f; unsigned u; } v; v.f = f;
    unsigned r = v.u + 0x7FFFu + ((v.u >> 16) & 1u);   // RNE
    return (ushort)(r >> 16);
}
__device__ __forceinline__ float bf2f(ushort h) {
    union { unsigned u; float f; } v; v.u = ((unsigned)h) << 16;
    return v.f;
}

// ---------------------------------------------------------------------------
// fp32 -> bf16 split (hi + lo residual), vectorized float4
// ---------------------------------------------------------------------------
__global__ __launch_bounds__(256)
void cvt_split_kernel(const float* __restrict__ src,
                      ushort* __restrict__ hi, ushort* __restrict__ lo, int n4)
{
    int i = blockIdx.x * blockDim.x + threadIdx.x;
    const int stride = gridDim.x * blockDim.x;
    for (; i < n4; i += stride) {
        float4 v = ((const float4*)src)[i];
        ushort4 h, l;
        h.x = f2bf(v.x); l.x = f2bf(v.x - bf2f(h.x));
        h.y = f2bf(v.y); l.y = f2bf(v.y - bf2f(h.y));
        h.z = f2bf(v.z); l.z = f2bf(v.z - bf2f(h.z));
        h.w = f2bf(v.w); l.w = f2bf(v.w - bf2f(h.w));
        ((ushort4*)hi)[i] = h;
        ((ushort4*)lo)[i] = l;
    }
}

// ---------------------------------------------------------------------------
// Transpose + split convert: src f32 [Z][K][N] -> dst bf16 [Z][N][K] (hi, lo)
// ---------------------------------------------------------------------------
__global__ __launch_bounds__(256)
void transpose_cvt_split_kernel(const float* __restrict__ src,
                                ushort* __restrict__ hi, ushort* __restrict__ lo,
                                int K, int N)
{
    __shared__ float T[64][68];
    const int k0 = blockIdx.x * 64;
    const int n0 = blockIdx.y * 64;
    const size_t zoff = (size_t)blockIdx.z * K * N;
    const int t = threadIdx.x;

    {
        const int c4 = t & 15;
        const int kr = t >> 4;
        #pragma unroll
        for (int j = 0; j < 4; ++j) {
            const int k = k0 + kr + 16 * j;
            float4 v = *(const float4*)&src[zoff + (size_t)k * N + n0 + c4 * 4];
            T[c4*4+0][kr + 16*j] = v.x;
            T[c4*4+1][kr + 16*j] = v.y;
            T[c4*4+2][kr + 16*j] = v.z;
            T[c4*4+3][kr + 16*j] = v.w;
        }
    }
    __syncthreads();
    {
        const int k4 = t & 15;
        const int nr = t >> 4;
        #pragma unroll
        for (int j = 0; j < 4; ++j) {
            const int nl = nr + 16 * j;
            ushort4 h, l;
            float x;
            x = T[nl][k4*4+0]; h.x = f2bf(x); l.x = f2bf(x - bf2f(h.x));
            x = T[nl][k4*4+1]; h.y = f2bf(x); l.y = f2bf(x - bf2f(h.y));
            x = T[nl][k4*4+2]; h.z = f2bf(x); l.z = f2bf(x - bf2f(h.z));
            x = T[nl][k4*4+3]; h.w = f2bf(x); l.w = f2bf(x - bf2f(h.w));
            const size_t o = zoff + (size_t)(n0 + nl) * K + k0 + k4 * 4;
            *(ushort4*)&hi[o] = h;
            *(ushort4*)&lo[o] = l;
        }
    }
}

// ---------------------------------------------------------------------------
// bf16x3 MFMA GEMM core (unchanged, measured 0 bank conflicts).
// ---------------------------------------------------------------------------
__device__ __forceinline__ void gemm_core_bf16x3(
    const ushort* __restrict__ Ahi, const ushort* __restrict__ Alo,
    const ushort* __restrict__ Bhi, const ushort* __restrict__ Blo,
    ushort* AsH, ushort* AsL, ushort* BsH, ushort* BsL,
    int m0, int n0, int t, f32x4v acc[4][4])
{
    const int l  = t & 63;
    const int w  = t >> 6;
    const int wr = w >> 1, wc = w & 1;
    const int lr = l & 15, lg = l >> 4;
    const int sc = t & 7;
    const int sr = t >> 3;

    for (int k0 = 0; k0 < NE; k0 += 64) {
        __syncthreads();
        #pragma unroll
        for (int j = 0; j < 4; ++j) {
            const int row  = sr + 32 * j;
            const int wofs = row * 64 + ((sc ^ (row & 7)) * 8);
            const size_t aofs = (size_t)(m0 + row) * NE + k0 + sc * 8;
            const size_t bofs = (size_t)(n0 + row) * NE + k0 + sc * 8;
            *(float4*)&AsH[wofs] = *(const float4*)(Ahi + aofs);
            *(float4*)&AsL[wofs] = *(const float4*)(Alo + aofs);
            *(float4*)&BsH[wofs] = *(const float4*)(Bhi + bofs);
            *(float4*)&BsL[wofs] = *(const float4*)(Blo + bofs);
        }
        __syncthreads();
        #pragma unroll
        for (int s = 0; s < 2; ++s) {
            bf16x8v afH[4], afL[4], bfH[4], bfL[4];
            #pragma unroll
            for (int i = 0; i < 4; ++i) {
                const int ra = wr * 64 + i * 16 + lr;
                const int ca = ((s * 4 + lg) ^ (ra & 7)) * 8;
                afH[i] = *(const bf16x8v*)&AsH[ra * 64 + ca];
                afL[i] = *(const bf16x8v*)&AsL[ra * 64 + ca];
                const int rb = wc * 64 + i * 16 + lr;
                const int cb = ((s * 4 + lg) ^ (rb & 7)) * 8;
                bfH[i] = *(const bf16x8v*)&BsH[rb * 64 + cb];
                bfL[i] = *(const bf16x8v*)&BsL[rb * 64 + cb];
            }
            #pragma unroll
            for (int i = 0; i < 4; ++i)
                #pragma unroll
                for (int j = 0; j < 4; ++j) {
                    acc[i][j] = __builtin_amdgcn_mfma_f32_16x16x32_bf16(afH[i], bfH[j], acc[i][j], 0, 0, 0);
                    acc[i][j] = __builtin_amdgcn_mfma_f32_16x16x32_bf16(afH[i], bfL[j], acc[i][j], 0, 0, 0);
                    acc[i][j] = __builtin_amdgcn_mfma_f32_16x16x32_bf16(afL[i], bfH[j], acc[i][j], 0, 0, 0);
                }
        }
    }
}

// ---------------------------------------------------------------------------
// QKV projection. z==0 -> Q (pre-scaled by D^-0.5), z==1 -> K, z==2 -> V.
// ALL outputs now bf16 hi/lo in [b,h,s,d].
// ---------------------------------------------------------------------------
__global__ __launch_bounds__(256, 2)
void gemm_qkv_kernel(const ushort* __restrict__ Xhi, const ushort* __restrict__ Xlo,
                     const ushort* __restrict__ WqH, const ushort* __restrict__ WqL,
                     const ushort* __restrict__ WkH, const ushort* __restrict__ WkL,
                     const ushort* __restrict__ WvH, const ushort* __restrict__ WvL,
                     ushort* __restrict__ Qhi, ushort* __restrict__ Qlo,
                     ushort* __restrict__ Khi, ushort* __restrict__ Klo,
                     ushort* __restrict__ Vhi, ushort* __restrict__ Vlo)
{
    __shared__ ushort AsH[128 * 64], AsL[128 * 64], BsH[128 * 64], BsL[128 * 64];
    const int z = blockIdx.z;
    const ushort* __restrict__ BtH = (z == 0) ? WqH : (z == 1) ? WkH : WvH;
    const ushort* __restrict__ BtL = (z == 0) ? WqL : (z == 1) ? WkL : WvL;
    const int m0 = blockIdx.x * 128;
    const int n0 = blockIdx.y * 128;
    const int t  = threadIdx.x;
    const int l  = t & 63;
    const int w  = t >> 6;
    const int wr = w >> 1, wc = w & 1;
    const int lr = l & 15, lg = l >> 4;

    f32x4v acc[4][4];
    #pragma unroll
    for (int i = 0; i < 4; ++i)
        #pragma unroll
        for (int j = 0; j < 4; ++j)
            #pragma unroll
            for (int q = 0; q < 4; ++q) acc[i][j][q] = 0.f;

    gemm_core_bf16x3(Xhi, Xlo, BtH, BtL, AsH, AsL, BsH, BsL, m0, n0, t, acc);

    ushort* __restrict__ Hi = (z == 0) ? Qhi : (z == 1) ? Khi : Vhi;
    ushort* __restrict__ Lo = (z == 0) ? Qlo : (z == 1) ? Klo : Vlo;
    const float qscale = (z == 0) ? 0.125f : 1.0f;

    #pragma unroll
    for (int i = 0; i < 4; ++i)
        #pragma unroll
        for (int j = 0; j < 4; ++j) {
            const int n  = n0 + wc * 64 + j * 16 + lr;
            const int hh = n >> 6, d = n & 63;
            #pragma unroll
            for (int q = 0; q < 4; ++q) {
                const int m  = m0 + wr * 64 + i * 16 + lg * 4 + q;
                const int bb = m >> 11, ss = m & 2047;
                const size_t idx = (((size_t)(bb * NH + hh)) * NS + ss) * ND + d;
                const float x = acc[i][j][q] * qscale;
                const ushort h = f2bf(x);
                Hi[idx] = h;
                Lo[idx] = f2bf(x - bf2f(h));
            }
        }
}

// ---------------------------------------------------------------------------
// Output projection (unchanged)
// ---------------------------------------------------------------------------
__global__ __launch_bounds__(256, 2)
void gemm_out_kernel(const ushort* __restrict__ AbH, const ushort* __restrict__ AbL,
                     const ushort* __restrict__ WoH, const ushort* __restrict__ WoL,
                     const float* __restrict__ bo,
                     float* __restrict__ Out)
{
    __shared__ ushort AsH[128 * 64], AsL[128 * 64], BsH[128 * 64], BsL[128 * 64];
    const int m0 = blockIdx.x * 128;
    const int n0 = blockIdx.y * 128;
    const int t  = threadIdx.x;
    const int l  = t & 63;
    const int w  = t >> 6;
    const int wr = w >> 1, wc = w & 1;
    const int lr = l & 15, lg = l >> 4;

    f32x4v acc[4][4];
    #pragma unroll
    for (int i = 0; i < 4; ++i)
        #pragma unroll
        for (int j = 0; j < 4; ++j)
            #pragma unroll
            for (int q = 0; q < 4; ++q) acc[i][j][q] = 0.f;

    gemm_core_bf16x3(AbH, AbL, WoH, WoL, AsH, AsL, BsH, BsL, m0, n0, t, acc);

    #pragma unroll
    for (int i = 0; i < 4; ++i)
        #pragma unroll
        for (int j = 0; j < 4; ++j) {
            const int n = n0 + wc * 64 + j * 16 + lr;
            const float bias = bo[n];
            #pragma unroll
            for (int q = 0; q < 4; ++q) {
                const int m = m0 + wr * 64 + i * 16 + lg * 4 + q;
                Out[(size_t)m * NE + n] = acc[i][j][q] + bias;
            }
        }
}

// ---------------------------------------------------------------------------
// Causal flash attention, all-MFMA (bf16x3 QK^T AND PV), fp32 softmax.
// Block = 256 thr (4 waves). Q-tile = 128 rows (32/wave), K-tile = 64.
// LDS: K[64][64] hi/lo + V^T[64][64] hi/lo + P[128][64] hi/lo = 64 KB.
// All LDS tiles use the XOR-chunk swizzle family measured at 0 conflicts.
// T14: next tile's K/V global loads issued before current tile's compute.
// Lane roles (MFMA): w=wave, g=lane>>4, c=lane&15.
//   S/O frag rows = 4g+q (D-layout, m89-verified this run), cols = c.
// ---------------------------------------------------------------------------
__global__ __launch_bounds__(256, 2)
void attn_kernel(const ushort* __restrict__ Qhi, const ushort* __restrict__ Qlo,
                 const ushort* __restrict__ Khi, const ushort* __restrict__ Klo,
                 const ushort* __restrict__ Vhi, const ushort* __restrict__ Vlo,
                 ushort* __restrict__ ObbH, ushort* __restrict__ ObbL)
{
    __shared__ ushort KsH[64 * 64], KsL[64 * 64];   // K  [key][d]   swizzled
    __shared__ ushort VTH[64 * 64], VTL[64 * 64];   // V^T [d][key]  swizzled
    __shared__ ushort PH[128 * 64], PL[128 * 64];   // P  [row][key] swizzled

    const int bh = blockIdx.x;
    const int qt = (int)gridDim.y - 1 - (int)blockIdx.y;   // heaviest first
    const int q0 = qt * 128;
    const int bb = bh >> 4, hh = bh & 15;
    const size_t base = (size_t)bh * NS * ND;

    const int t = threadIdx.x;
    const int l = t & 63;
    const int w = t >> 6;
    const int g = l >> 4;
    const int c = l & 15;
    const int sc = t & 7, sr = t >> 3;   // K staging roles

    // Q fragments: rows q0+32w+16r+c, k = 32s+8g+j (consistent k-map)
    bf16x8v qh[2][2], ql[2][2];
    #pragma unroll
    for (int r = 0; r < 2; ++r) {
        const size_t qrow = base + (size_t)(q0 + 32 * w + 16 * r + c) * ND;
        #pragma unroll
        for (int s = 0; s < 2; ++s) {
            qh[r][s] = *(const bf16x8v*)&Qhi[qrow + s * 32 + g * 8];
            ql[r][s] = *(const bf16x8v*)&Qlo[qrow + s * 32 + g * 8];
        }
    }

    float m_run[2][4], l_run[2][4];
    f32x4v o_acc[2][4];
    #pragma unroll
    for (int r = 0; r < 2; ++r)
        #pragma unroll
        for (int q = 0; q < 4; ++q) {
            m_run[r][q] = -INFINITY;
            l_run[r][q] = 0.f;
        }
    #pragma unroll
    for (int r = 0; r < 2; ++r)
        #pragma unroll
        for (int n = 0; n < 4; ++n)
            #pragma unroll
            for (int q = 0; q < 4; ++q) o_acc[r][n][q] = 0.f;

    const int nt = 2 * qt + 2;   // 64-key tiles: j0 = 0 .. q0+64

    // prefetch regs (T14)
    float4 kst_h[2], kst_l[2];
    u16x8v vst_h[2], vst_l[2];
    {   // tile 0 loads
        #pragma unroll
        for (int rr = 0; rr < 2; ++rr) {
            const size_t ko = base + (size_t)(sr + 32 * rr) * ND + sc * 8;
            kst_h[rr] = *(const float4*)&Khi[ko];
            kst_l[rr] = *(const float4*)&Klo[ko];
        }
        const size_t vo = base + (size_t)l * ND + w * 16;
        vst_h[0] = *(const u16x8v*)&Vhi[vo];
        vst_h[1] = *(const u16x8v*)&Vhi[vo + 8];
        vst_l[0] = *(const u16x8v*)&Vlo[vo];
        vst_l[1] = *(const u16x8v*)&Vlo[vo + 8];
    }

    for (int it = 0; it < nt; ++it) {
        const int j0 = it * 64;
        __syncthreads();   // A: prev tile's PV done reading K/VT/P

        // staged regs -> LDS
        #pragma unroll
        for (int rr = 0; rr < 2; ++rr) {
            const int row  = sr + 32 * rr;
            const int wofs = row * 64 + ((sc ^ (row & 7)) * 8);
            *(float4*)&KsH[wofs] = kst_h[rr];
            *(float4*)&KsL[wofs] = kst_l[rr];
        }
        #pragma unroll
        for (int e = 0; e < 16; ++e) {
            const int d   = w * 16 + e;
            const int ofs = d * 64 + (((l >> 3) ^ (e & 7)) * 8) + (l & 7);
            VTH[ofs] = (e < 8) ? vst_h[0][e] : vst_h[1][e - 8];
            VTL[ofs] = (e < 8) ? vst_l[0][e] : vst_l[1][e - 8];
        }
        __syncthreads();   // B: K/VT visible

        // T14: issue next tile's global loads now (land during compute)
        if (it + 1 < nt) {
            const int j1 = j0 + 64;
            #pragma unroll
            for (int rr = 0; rr < 2; ++rr) {
                const size_t ko = base + (size_t)(j1 + sr + 32 * rr) * ND + sc * 8;
                kst_h[rr] = *(const float4*)&Khi[ko];
                kst_l[rr] = *(const float4*)&Klo[ko];
            }
            const size_t vo = base + (size_t)(j1 + l) * ND + w * 16;
            vst_h[0] = *(const u16x8v*)&Vhi[vo];
            vst_h[1] = *(const u16x8v*)&Vhi[vo + 8];
            vst_l[0] = *(const u16x8v*)&Vlo[vo];
            vst_l[1] = *(const u16x8v*)&Vlo[vo + 8];
        }

        // QK^T (bf16x3): sf[r][f][q] = S[q0+32w+16r+4g+q][j0+16f+c]
        f32x4v sf[2][4];
        #pragma unroll
        for (int r = 0; r < 2; ++r)
            #pragma unroll
            for (int f = 0; f < 4; ++f)
                #pragma unroll
                for (int q = 0; q < 4; ++q) sf[r][f][q] = 0.f;
        #pragma unroll
        for (int s = 0; s < 2; ++s)
            #pragma unroll
            for (int f = 0; f < 4; ++f) {
                const int rb = 16 * f + c;
                const int cb = ((4 * s + g) ^ (rb & 7)) * 8;
                bf16x8v kh = *(const bf16x8v*)&KsH[rb * 64 + cb];
                bf16x8v kl = *(const bf16x8v*)&KsL[rb * 64 + cb];
                #pragma unroll
                for (int r = 0; r < 2; ++r) {
                    sf[r][f] = __builtin_amdgcn_mfma_f32_16x16x32_bf16(qh[r][s], kh, sf[r][f], 0, 0, 0);
                    sf[r][f] = __builtin_amdgcn_mfma_f32_16x16x32_bf16(qh[r][s], kl, sf[r][f], 0, 0, 0);
                    sf[r][f] = __builtin_amdgcn_mfma_f32_16x16x32_bf16(ql[r][s], kh, sf[r][f], 0, 0, 0);
                }
            }

        // causal mask (needed iff some key can exceed this wave's min row)
        if (j0 + 63 > q0 + 32 * w) {
            #pragma unroll
            for (int f = 0; f < 4; ++f) {
                const int key = j0 + 16 * f + c;
                #pragma unroll
                for (int r = 0; r < 2; ++r) {
                    const int rowb = q0 + 32 * w + 16 * r + 4 * g;
                    #pragma unroll
                    for (int q = 0; q < 4; ++q)
                        if (key > rowb + q) sf[r][f][q] = -INFINITY;
                }
            }
        }

        // online softmax (reduce across the 16 c-lanes; lanes differing in g
        // hold different rows and are untouched by xor 1/2/4/8)
        float fac[2][4];
        #pragma unroll
        for (int r = 0; r < 2; ++r)
            #pragma unroll
            for (int q = 0; q < 4; ++q) {
                float rm = fmaxf(fmaxf(sf[r][0][q], sf[r][1][q]),
                                 fmaxf(sf[r][2][q], sf[r][3][q]));
                rm = fmaxf(rm, __shfl_xor(rm, 1));
                rm = fmaxf(rm, __shfl_xor(rm, 2));
                rm = fmaxf(rm, __shfl_xor(rm, 4));
                rm = fmaxf(rm, __shfl_xor(rm, 8));
                const float mn = fmaxf(m_run[r][q], rm);
                float rs = 0.f;
                #pragma unroll
                for (int f = 0; f < 4; ++f) {
                    const float p = __expf(sf[r][f][q] - mn);  // exp(-inf)=0
                    sf[r][f][q] = p;
                    rs += p;
                }
                rs += __shfl_xor(rs, 1);
                rs += __shfl_xor(rs, 2);
                rs += __shfl_xor(rs, 4);
                rs += __shfl_xor(rs, 8);
                fac[r][q] = __expf(m_run[r][q] - mn);
                m_run[r][q] = mn;
                l_run[r][q] = l_run[r][q] * fac[r][q] + rs;
            }

        // P -> LDS as bf16 hi/lo, [row][key], XOR-chunk swizzle
        #pragma unroll
        for (int r = 0; r < 2; ++r)
            #pragma unroll
            for (int f = 0; f < 4; ++f) {
                const int key = 16 * f + c;
                #pragma unroll
                for (int q = 0; q < 4; ++q) {
                    const int row = 32 * w + 16 * r + 4 * g + q;
                    const int ofs = row * 64 + (((key >> 3) ^ (row & 7)) * 8) + (key & 7);
                    const float x = sf[r][f][q];
                    const ushort h = f2bf(x);
                    PH[ofs] = h;
                    PL[ofs] = f2bf(x - bf2f(h));
                }
            }
        __syncthreads();   // C: P visible

        // rescale o_acc in-register (same lanes own S rows and O rows)
        #pragma unroll
        for (int r = 0; r < 2; ++r)
            #pragma unroll
            for (int n = 0; n < 4; ++n)
                #pragma unroll
                for (int q = 0; q < 4; ++q) o_acc[r][n][q] *= fac[r][q];

        // PV (bf16x3): O[row][d] += P[row][key] * V[key][d]
        #pragma unroll
        for (int s = 0; s < 2; ++s) {
            bf16x8v pa_h[2], pa_l[2];
            #pragma unroll
            for (int r = 0; r < 2; ++r) {
                const int rowA = 32 * w + 16 * r + c;
                const int ca   = (((4 * s + g) ^ (rowA & 7)) * 8);
                pa_h[r] = *(const bf16x8v*)&PH[rowA * 64 + ca];
                pa_l[r] = *(const bf16x8v*)&PL[rowA * 64 + ca];
            }
            #pragma unroll
            for (int n = 0; n < 4; ++n) {
                const int colB = 16 * n + c;
                const int cb   = (((4 * s + g) ^ (colB & 7)) * 8);
                bf16x8v vh = *(const bf16x8v*)&VTH[colB * 64 + cb];
                bf16x8v vl = *(const bf16x8v*)&VTL[colB * 64 + cb];
                #pragma unroll
                for (int r = 0; r < 2; ++r) {
                    o_acc[r][n] = __builtin_amdgcn_mfma_f32_16x16x32_bf16(pa_h[r], vh, o_acc[r][n], 0, 0, 0);
                    o_acc[r][n] = __builtin_amdgcn_mfma_f32_16x16x32_bf16(pa_h[r], vl, o_acc[r][n], 0, 0, 0);
                    o_acc[r][n] = __builtin_amdgcn_mfma_f32_16x16x32_bf16(pa_l[r], vh, o_acc[r][n], 0, 0, 0);
                }
            }
        }
    }

    // epilogue: normalize and split-store O as bf16 hi/lo [b,s,h,d]
    #pragma unroll
    for (int r = 0; r < 2; ++r)
        #pragma unroll
        for (int q = 0; q < 4; ++q) {
            const float inv = 1.f / l_run[r][q];
            const int srow = q0 + 32 * w + 16 * r + 4 * g + q;
            #pragma unroll
            for (int n = 0; n < 4; ++n) {
                const size_t o = ((size_t)(bb * NS + srow) * NH + hh) * 64 + 16 * n + c;
                const float x = o_acc[r][n][q] * inv;
                const ushort h = f2bf(x);
                ObbH[o] = h;
                ObbL[o] = f2bf(x - bf2f(h));
            }
        }
}

// ---------------------------------------------------------------------------
extern "C" void kernel_launch(void* const* d_in, const int* in_sizes, int n_in,
                              void* d_out, int out_size, void* d_ws, size_t ws_size,
                              hipStream_t stream)
{
    (void)in_sizes; (void)n_in; (void)out_size; (void)ws_size;
    const float* X  = (const float*)d_in[0];
    const float* Wq = (const float*)d_in[1];
    const float* Wk = (const float*)d_in[2];
    const float* Wv = (const float*)d_in[3];
    const float* Wo = (const float*)d_in[4];
    const float* bo = (const float*)d_in[5];

    // workspace (~151 MB) with dead-region aliasing
    char* p = (char*)d_ws;
    ushort* Xhi = (ushort*)p; p += (size_t)NM * NE * 2;     // 16.8 MB
    ushort* Xlo = (ushort*)p; p += (size_t)NM * NE * 2;     // 16.8 MB
    ushort* WqH = (ushort*)p; p += (size_t)NE * NE * 2;
    ushort* WqL = (ushort*)p; p += (size_t)NE * NE * 2;
    ushort* WkH = (ushort*)p; p += (size_t)NE * NE * 2;
    ushort* WkL = (ushort*)p; p += (size_t)NE * NE * 2;
    ushort* WvH = (ushort*)p; p += (size_t)NE * NE * 2;
    ushort* WvL = (ushort*)p; p += (size_t)NE * NE * 2;
    ushort* WoH = (ushort*)p; p += (size_t)NE * NE * 2;
    ushort* WoL = (ushort*)p; p += (size_t)NE * NE * 2;
    ushort* Qhi = (ushort*)p; p += (size_t)NM * NE * 2;     // 16.8 MB
    ushort* Qlo = (ushort*)p; p += (size_t)NM * NE * 2;
    ushort* Khi = (ushort*)p; p += (size_t)NM * NE * 2;
    ushort* Klo = (ushort*)p; p += (size_t)NM * NE * 2;
    ushort* Vhi = (ushort*)p; p += (size_t)NM * NE * 2;
    ushort* Vlo = (ushort*)p; p += (size_t)NM * NE * 2;
    // aliases over dead regions (X splits dead after gemm_qkv; attn doesn't
    // read them, so attn may write its bf16 output there):
    ushort* ObbH = Xhi;
    ushort* ObbL = Xlo;

    // 1. split-convert X
    hipLaunchKernelGGL(cvt_split_kernel, dim3(2048), dim3(256), 0, stream,
                       X, Xhi, Xlo, NM * NE / 4);
    // 2. transpose + split-convert weights to n-major bf16
    hipLaunchKernelGGL(transpose_cvt_split_kernel, dim3(16, 1, 16), dim3(256), 0, stream,
                       Wq, WqH, WqL, NE, ND);
    hipLaunchKernelGGL(transpose_cvt_split_kernel, dim3(16, 1, 16), dim3(256), 0, stream,
                       Wk, WkH, WkL, NE, ND);
    hipLaunchKernelGGL(transpose_cvt_split_kernel, dim3(16, 1, 16), dim3(256), 0, stream,
                       Wv, WvH, WvL, NE, ND);
    hipLaunchKernelGGL(transpose_cvt_split_kernel, dim3(16, 16, 1), dim3(256), 0, stream,
                       Wo, WoH, WoL, NE, NE);
    // 3. QKV projection: Q (pre-scaled), K, V -> bf16 hi/lo [b,h,s,d]
    hipLaunchKernelGGL(gemm_qkv_kernel, dim3(NM/128, NE/128, 3), dim3(256), 0, stream,
                       Xhi, Xlo, WqH, WqL, WkH, WkL, WvH, WvL,
                       Qhi, Qlo, Khi, Klo, Vhi, Vlo);
    // 4. attention (all-MFMA bf16x3, fp32 softmax) -> bf16 hi/lo [b,s,h*d]
    hipLaunchKernelGGL(attn_kernel, dim3(NB*NH, NS/128), dim3(256), 0, stream,
                       Qhi, Qlo, Khi, Klo, Vhi, Vlo, ObbH, ObbL);
    // 5. output projection (bf16x3 MFMA) + bias -> d_out
    hipLaunchKernelGGL(gemm_out_kernel, dim3(NM/128, NE/128), dim3(256), 0, stream,
                       ObbH, ObbL, WoH, WoL, bo, (float*)d_out);
}